// Round 5
// baseline (809.962 us; speedup 1.0000x reference)
//
#include <hip/hip_runtime.h>
#include <math.h>

// Problem constants (T5 encoder self-attention)
#define H_    16
#define S_    2048
#define DH_   64
#define DM_   1024
#define NTOK_ 4096          // B*S
#define NBIAS_ 4095         // 2*S-1 distinct relative positions

typedef __attribute__((ext_vector_type(8))) short short8;  // 8 bf16 (4 VGPRs)
typedef __attribute__((ext_vector_type(4))) float f32x4;   // MFMA C/D frag

#define MFMA16(a, b, c) __builtin_amdgcn_mfma_f32_16x16x32_bf16((a), (b), (c), 0, 0, 0)

__device__ __forceinline__ ushort f2bf(float f) {
  union { float f; unsigned u; } x; x.f = f;
  unsigned r = (x.u + 0x7FFFu + ((x.u >> 16) & 1u)) >> 16;  // RNE
  return (ushort)r;
}
__device__ __forceinline__ ushort f2bf_fast(float f) {       // round-half-up
  union { float f; unsigned u; } x; x.f = f;
  return (ushort)((x.u + 0x8000u) >> 16);
}

// global (16B per lane) -> LDS at wave-uniform base + lane*16.
__device__ __forceinline__ void ldg16_lds(const ushort* g, ushort* l) {
  __builtin_amdgcn_global_load_lds(
      (const __attribute__((address_space(1))) unsigned int*)g,
      (__attribute__((address_space(3))) unsigned int*)l, 16, 0, 0);
}

// ---------------- fp32 -> bf16 cast ----------------
__global__ void cast_bf16_k(const float* __restrict__ in, ushort* __restrict__ out, int n) {
  int i = (blockIdx.x * blockDim.x + threadIdx.x) * 4;
  if (i >= n) return;
  const float4 v = *(const float4*)(in + i);
  ushort4 o;
  o.x = f2bf(v.x); o.y = f2bf(v.y); o.z = f2bf(v.z); o.w = f2bf(v.w);
  *(ushort4*)(out + i) = o;
}

// ---------------- T5 relative-position bias table ----------------
__global__ void build_bias_k(const float* __restrict__ rel_emb, float* __restrict__ biasTab) {
  int d = blockIdx.x * blockDim.x + threadIdx.x;
  if (d >= NBIAS_) return;
  int rp = d - (S_ - 1);
  int ret = (rp > 0) ? 16 : 0;
  int arp = rp < 0 ? -rp : rp;
  int bucket;
  if (arp < 8) {
    bucket = ret + arp;
  } else {
    float t = logf((float)arp * 0.125f);
    t = t / 2.772588722239781f;
    t = t * 8.0f;
    int large = 8 + (int)t;
    if (large > 15) large = 15;
    bucket = ret + large;
  }
  for (int h = 0; h < H_; ++h)
    biasTab[h * NBIAS_ + d] = rel_emb[bucket * H_ + h];
}

// ---------------- shared BK=64 GEMM core: C(128x128) = A @ B^T ----------------
// XOR-swizzled LDS (16B slot ^= row&7): frag ds_read_b128 lands ~2-way (free).
__device__ __forceinline__ void gemm_core(
    const ushort* __restrict__ gA, const ushort* __restrict__ gB,
    ushort* As, ushort* Bs, f32x4 (&acc)[4][4],
    int m0, int n0, int wave, int lane)
{
  const int l15 = lane & 15, quad = lane >> 4;
  const int wm = wave >> 1, wn = wave & 1;
  const int srow = lane >> 3;
  const int sw = ((lane & 7) ^ (lane >> 3)) * 8;   // swizzled source col
  const int px = l15 & 7;

  for (int k0 = 0; k0 < DM_; k0 += 64) {
    __syncthreads();
#pragma unroll
    for (int i = 0; i < 8; ++i) {
      int c = wave * 8 + i;                         // 0..31: 16 A-chunks, 16 B-chunks
      if (c < 16)
        ldg16_lds(gA + (size_t)(m0 + c * 8 + srow) * DM_ + k0 + sw, As + c * 512);
      else
        ldg16_lds(gB + (size_t)(n0 + (c - 16) * 8 + srow) * DM_ + k0 + sw, Bs + (c - 16) * 512);
    }
    __syncthreads();
#pragma unroll
    for (int kk = 0; kk < 2; ++kk) {
      short8 af[4], bfr[4];
#pragma unroll
      for (int mi = 0; mi < 4; ++mi)
        af[mi] = *(const short8*)&As[(wm * 64 + mi * 16 + l15) * 64 + (((kk * 4 + quad) ^ px)) * 8];
#pragma unroll
      for (int ni = 0; ni < 4; ++ni)
        bfr[ni] = *(const short8*)&Bs[(wn * 64 + ni * 16 + l15) * 64 + (((kk * 4 + quad) ^ px)) * 8];
#pragma unroll
      for (int mi = 0; mi < 4; ++mi)
#pragma unroll
        for (int ni = 0; ni < 4; ++ni)
          acc[mi][ni] = MFMA16(af[mi], bfr[ni], acc[mi][ni]);
    }
  }
}

// ---------------- QKV projection ----------------
// z: 0->Q [b,h,s,dh], 1->K [b,h,s,dh], 2->V^T [b,h,dh,s] (via LDS transpose, coalesced)
__global__ __launch_bounds__(256) void gemm_qkv_k(
    const ushort* __restrict__ X,
    const ushort* __restrict__ Wq, const ushort* __restrict__ Wk, const ushort* __restrict__ Wv,
    ushort* __restrict__ Q, ushort* __restrict__ K, ushort* __restrict__ Vt)
{
  __shared__ __align__(16) ushort sh[17408];      // 34 KB: As|Bs (8K+8K), or 128x136 transpose
  ushort* As = sh;
  ushort* Bs = sh + 8192;
  const int z = blockIdx.z;
  const ushort* __restrict__ W = (z == 0) ? Wq : (z == 1) ? Wk : Wv;
  const int tid = threadIdx.x;
  const int wave = tid >> 6, lane = tid & 63;
  const int l15 = lane & 15, quad = lane >> 4;
  const int wm = wave >> 1, wn = wave & 1;
  const int m0 = blockIdx.y * 128;
  const int n0 = blockIdx.x * 128;

  f32x4 acc[4][4];
#pragma unroll
  for (int mi = 0; mi < 4; ++mi)
#pragma unroll
    for (int ni = 0; ni < 4; ++ni) acc[mi][ni] = (f32x4){0.f, 0.f, 0.f, 0.f};

  gemm_core(X, W, As, Bs, acc, m0, n0, wave, lane);

  if (z < 2) {
    ushort* dst = (z == 0) ? Q : K;
#pragma unroll
    for (int mi = 0; mi < 4; ++mi)
#pragma unroll
      for (int ni = 0; ni < 4; ++ni)
#pragma unroll
        for (int r = 0; r < 4; ++r) {
          int m = m0 + wm * 64 + mi * 16 + quad * 4 + r;   // token
          int n = n0 + wn * 64 + ni * 16 + l15;            // d_model col
          int b = m >> 11, s = m & (S_ - 1);
          int hh = n >> 6, dd = n & 63;
          dst[((size_t)(b * H_ + hh) * S_ + s) * DH_ + dd] = f2bf(acc[mi][ni][r]);
        }
  } else {
    // transpose through LDS -> coalesced b128 stores of V^T
    __syncthreads();
#pragma unroll
    for (int mi = 0; mi < 4; ++mi)
#pragma unroll
      for (int ni = 0; ni < 4; ++ni) {
        int n = wn * 64 + ni * 16 + l15;
        int m = wm * 64 + mi * 16 + quad * 4;
        ushort4 w4;
        w4.x = f2bf(acc[mi][ni][0]); w4.y = f2bf(acc[mi][ni][1]);
        w4.z = f2bf(acc[mi][ni][2]); w4.w = f2bf(acc[mi][ni][3]);
        *(ushort4*)&sh[n * 136 + m] = w4;                  // stride 136 -> conflict-light
      }
    __syncthreads();
    const int b = m0 >> 11, s0 = m0 & (S_ - 1);
#pragma unroll
    for (int p = 0; p < 8; ++p) {
      int task = p * 256 + tid;              // 128 n x 16 m-chunks
      int n = task >> 4, mc = (task & 15) * 8;
      int col = n0 + n, hh = col >> 6, dd = col & 63;
      *(short8*)(Vt + ((size_t)(b * H_ + hh) * DH_ + dd) * S_ + s0 + mc) =
          *(const short8*)&sh[n * 136 + mc];
    }
  }
}

// ---------------- Output projection: out = Ctx @ Wo^T (fp32) ----------------
__global__ __launch_bounds__(256) void gemm_out_k(
    const ushort* __restrict__ A, const ushort* __restrict__ W, float* __restrict__ out)
{
  __shared__ __align__(16) ushort sh[16384];
  ushort* As = sh;
  ushort* Bs = sh + 8192;
  const int tid = threadIdx.x;
  const int wave = tid >> 6, lane = tid & 63;
  const int l15 = lane & 15, quad = lane >> 4;
  const int wm = wave >> 1, wn = wave & 1;
  const int m0 = blockIdx.y * 128;
  const int n0 = blockIdx.x * 128;

  f32x4 acc[4][4];
#pragma unroll
  for (int mi = 0; mi < 4; ++mi)
#pragma unroll
    for (int ni = 0; ni < 4; ++ni) acc[mi][ni] = (f32x4){0.f, 0.f, 0.f, 0.f};

  gemm_core(A, W, As, Bs, acc, m0, n0, wave, lane);

#pragma unroll
  for (int mi = 0; mi < 4; ++mi)
#pragma unroll
    for (int ni = 0; ni < 4; ++ni)
#pragma unroll
      for (int r = 0; r < 4; ++r) {
        int m = m0 + wm * 64 + mi * 16 + quad * 4 + r;
        int n = n0 + wn * 64 + ni * 16 + l15;
        out[(size_t)m * DM_ + n] = acc[mi][ni][r];
      }
}

// ---------------- Flash attention: key-sliced waves, transposed QK, P in registers ----------------
// Block: 4 waves, 64 q-rows, full 2048 keys in 64-key tiles. Wave w owns key slice
// [w*16, w*16+16) of every tile. S^T = K·Q^T (A=K, B=Q) puts P directly in the
// A-operand layout of a half-zeroed 16x16x32 PV mfma -> no P LDS round-trip.
// No online max (scores bounded; softmax shift-invariant); partial O/l are additive
// across waves -> one LDS reduce at the end. K/V staged via XOR-swizzled ldg16.
__global__ __launch_bounds__(256, 2) void attn_k(
    const ushort* __restrict__ Q, const ushort* __restrict__ K, const ushort* __restrict__ Vt,
    const float* __restrict__ biasTab, ushort* __restrict__ Ctx)
{
  __shared__ __align__(16) ushort KV[8192];   // Ks[64key][64dh] | Vs[64dh][64key], swizzled
  __shared__ float bias_s[2111];              // this block's bias window
  ushort* Ks = KV;
  ushort* Vs = KV + 4096;

  const int tid = threadIdx.x;
  const int wave = tid >> 6, lane = tid & 63;  // wave = key-slice id
  const int l15 = lane & 15, quad = lane >> 4;
  const int bh = blockIdx.y;
  const int h = bh & (H_ - 1);
  const int b = bh >> 4;
  const int qb = blockIdx.x * 64;
  const int srow = lane >> 3;
  const int sw = ((lane & 7) ^ (lane >> 3)) * 8;  // swizzled source col (elements)

  const f32x4 zero4 = {0.f, 0.f, 0.f, 0.f};

  // bias_s[i] = bias[delta + 2047] with i = delta + qb + 63
  for (int i = tid; i < 2111; i += 256)
    bias_s[i] = biasTab[h * NBIAS_ + 1984 - qb + i];

  const ushort* Qh = Q  + (size_t)bh * S_ * DH_;
  const ushort* Kh = K  + (size_t)bh * S_ * DH_;
  const ushort* Vh = Vt + (size_t)bh * DH_ * S_;

  // Q B-frags: B[n=qrow=l15][k=dh], 64 rows x 64 dh -> 8 frags, kept in registers
  short8 qf[4][2];
#pragma unroll
  for (int nf = 0; nf < 4; ++nf)
#pragma unroll
    for (int kk = 0; kk < 2; ++kk)
      qf[nf][kk] = *(const short8*)(Qh + (size_t)(qb + nf * 16 + l15) * DH_ + kk * 32 + quad * 8);

  short8 oneh;                                 // {1,1,1,1,0,0,0,0} bf16
#pragma unroll
  for (int i = 0; i < 8; ++i) oneh[i] = (i < 4) ? (short)0x3F80 : (short)0;

  f32x4 of[4][4];                              // O[qrow nf][dh nt] partial
#pragma unroll
  for (int nf = 0; nf < 4; ++nf)
#pragma unroll
    for (int nt = 0; nt < 4; ++nt) of[nf][nt] = zero4;
  f32x4 ls[4];
#pragma unroll
  for (int nf = 0; nf < 4; ++nf) ls[nf] = zero4;

  const int kidx = (wave * 16 + l15) * 64;     // K row base (elements)
  const int vslot = wave * 2 + (quad >> 1);    // V logical 16B slot for this wave/quad

  for (int kt = 0; kt < S_; kt += 64) {
    __syncthreads();                           // prior tile's LDS reads done
#pragma unroll
    for (int i = 0; i < 2; ++i) {              // 16 chunks / 4 waves: K chunks 0..7, V 8..15
      int c = wave * 2 + i;
      ldg16_lds(Kh + (size_t)(kt + c * 8 + srow) * DH_ + sw, Ks + c * 512);
      ldg16_lds(Vh + (size_t)(c * 8 + srow) * S_ + kt + sw, Vs + c * 512);
    }
    __syncthreads();                           // drains vmcnt

    // ---- S^T = K·Q^T for this wave's 16 keys x 64 q-rows ----
    short8 kf0 = *(const short8*)&Ks[kidx + ((quad ^ (l15 & 7))) * 8];
    short8 kf1 = *(const short8*)&Ks[kidx + (((4 + quad) ^ (l15 & 7))) * 8];
    f32x4 sc[4];
#pragma unroll
    for (int nf = 0; nf < 4; ++nf) {
      sc[nf] = MFMA16(kf0, qf[nf][0], zero4);
      sc[nf] = MFMA16(kf1, qf[nf][1], sc[nf]);
    }

    // ---- bias + exp (no max); result packed straight into PV A-frags ----
    short8 pf[4];
    const int ib = kt + wave * 16 + quad * 4 + 63 - l15;
#pragma unroll
    for (int nf = 0; nf < 4; ++nf) {
      const int i0 = ib - nf * 16;
      pf[nf][0] = (short)f2bf_fast(__expf(sc[nf][0] * 0.125f + bias_s[i0]));
      pf[nf][1] = (short)f2bf_fast(__expf(sc[nf][1] * 0.125f + bias_s[i0 + 1]));
      pf[nf][2] = (short)f2bf_fast(__expf(sc[nf][2] * 0.125f + bias_s[i0 + 2]));
      pf[nf][3] = (short)f2bf_fast(__expf(sc[nf][3] * 0.125f + bias_s[i0 + 3]));
      pf[nf][4] = 0; pf[nf][5] = 0; pf[nf][6] = 0; pf[nf][7] = 0;
    }

    // ---- row-sum + PV (half-zero k=16 mfma) ----
#pragma unroll
    for (int nf = 0; nf < 4; ++nf) ls[nf] = MFMA16(pf[nf], oneh, ls[nf]);
#pragma unroll
    for (int nt = 0; nt < 4; ++nt) {
      ushort4 v4 = *(const ushort4*)&Vs[(nt * 16 + l15) * 64 +
                                        ((vslot ^ (l15 & 7))) * 8 + (quad & 1) * 4];
      short8 vf;
      vf[0] = (short)v4.x; vf[1] = (short)v4.y; vf[2] = (short)v4.z; vf[3] = (short)v4.w;
      vf[4] = 0; vf[5] = 0; vf[6] = 0; vf[7] = 0;
#pragma unroll
      for (int nf = 0; nf < 4; ++nf)
        of[nf][nt] = MFMA16(pf[nf], vf, of[nf][nt]);
    }
  }

  // ---- cross-wave reduce (partials additive) + store ----
  __syncthreads();
  float* red = (float*)KV;                     // 16 KB scratch
#pragma unroll 1
  for (int mi = 0; mi < 4; ++mi) {
    if (wave) {
      int base = ((wave - 1) * 64 + lane) * 21;
#pragma unroll
      for (int nt = 0; nt < 4; ++nt)
#pragma unroll
        for (int r = 0; r < 4; ++r) red[base + nt * 4 + r] = of[mi][nt][r];
#pragma unroll
      for (int r = 0; r < 4; ++r) red[base + 16 + r] = ls[mi][r];
    }
    __syncthreads();
    if (wave == 0) {
#pragma unroll
      for (int w = 1; w < 4; ++w) {
        int base = ((w - 1) * 64 + lane) * 21;
#pragma unroll
        for (int nt = 0; nt < 4; ++nt)
#pragma unroll
          for (int r = 0; r < 4; ++r) of[mi][nt][r] += red[base + nt * 4 + r];
#pragma unroll
        for (int r = 0; r < 4; ++r) ls[mi][r] += red[base + 16 + r];
      }
#pragma unroll
      for (int nt = 0; nt < 4; ++nt)
#pragma unroll
        for (int r = 0; r < 4; ++r) {
          int t = b * S_ + qb + mi * 16 + quad * 4 + r;
          Ctx[(size_t)t * DM_ + h * 64 + nt * 16 + l15] = f2bf(of[mi][nt][r] / ls[mi][r]);
        }
    }
    __syncthreads();
  }
}

// ---------------- launch ----------------
extern "C" void kernel_launch(void* const* d_in, const int* in_sizes, int n_in,
                              void* d_out, int out_size, void* d_ws, size_t ws_size,
                              hipStream_t stream) {
  const float* hs  = (const float*)d_in[0];
  const float* Wq  = (const float*)d_in[1];
  const float* Wk  = (const float*)d_in[2];
  const float* Wv  = (const float*)d_in[3];
  const float* Wo  = (const float*)d_in[4];
  const float* rel = (const float*)d_in[5];
  float* out = (float*)d_out;

  ushort* Xb  = (ushort*)d_ws;                          // 4096x1024
  ushort* Wqb = Xb  + (size_t)NTOK_ * DM_;              // 1024x1024 each
  ushort* Wkb = Wqb + (size_t)DM_ * DM_;
  ushort* Wvb = Wkb + (size_t)DM_ * DM_;
  ushort* Wob = Wvb + (size_t)DM_ * DM_;
  ushort* Qd  = Wob + (size_t)DM_ * DM_;                // [b][h][s][dh]
  ushort* Kd  = Qd  + (size_t)NTOK_ * DM_;
  ushort* Vtd = Kd  + (size_t)NTOK_ * DM_;              // [b][h][dh][s]
  float* biasTab = (float*)(Vtd + (size_t)NTOK_ * DM_); // [H][4095]
  ushort* Ctx = Xb;                                     // alias: X dead after QKV GEMM

  cast_bf16_k<<<4096, 256, 0, stream>>>(hs, Xb, NTOK_ * DM_);
  cast_bf16_k<<<1024, 256, 0, stream>>>(Wq, Wqb, DM_ * DM_);
  cast_bf16_k<<<1024, 256, 0, stream>>>(Wk, Wkb, DM_ * DM_);
  cast_bf16_k<<<1024, 256, 0, stream>>>(Wv, Wvb, DM_ * DM_);
  cast_bf16_k<<<1024, 256, 0, stream>>>(Wo, Wob, DM_ * DM_);
  build_bias_k<<<16, 256, 0, stream>>>(rel, biasTab);

  gemm_qkv_k<<<dim3(8, 32, 3), 256, 0, stream>>>(Xb, Wqb, Wkb, Wvb, Qd, Kd, Vtd);
  attn_k<<<dim3(S_ / 64, 2 * H_), 256, 0, stream>>>(Qd, Kd, Vtd, biasTab, Ctx);
  gemm_out_k<<<dim3(8, 32), 256, 0, stream>>>(Ctx, Wob, out);
}

// Round 6
// 242.434 us; speedup vs baseline: 3.3410x; 3.3410x over previous
//
#include <hip/hip_runtime.h>
#include <math.h>

// Problem constants (T5 encoder self-attention)
#define H_    16
#define S_    2048
#define DH_   64
#define DM_   1024
#define NTOK_ 4096          // B*S
#define NBIAS_ 4095         // 2*S-1 distinct relative positions

typedef __attribute__((ext_vector_type(8))) short short8;  // 8 bf16 (4 VGPRs)
typedef __attribute__((ext_vector_type(4))) float f32x4;   // MFMA C/D frag

#define MFMA16(a, b, c) __builtin_amdgcn_mfma_f32_16x16x32_bf16((a), (b), (c), 0, 0, 0)

__device__ __forceinline__ ushort f2bf(float f) {
  union { float f; unsigned u; } x; x.f = f;
  unsigned r = (x.u + 0x7FFFu + ((x.u >> 16) & 1u)) >> 16;  // RNE
  return (ushort)r;
}
__device__ __forceinline__ ushort f2bf_fast(float f) {       // round-half-up
  union { float f; unsigned u; } x; x.f = f;
  return (ushort)((x.u + 0x8000u) >> 16);
}

// global (16B per lane) -> LDS at wave-uniform base + lane*16.
__device__ __forceinline__ void ldg16_lds(const ushort* g, ushort* l) {
  __builtin_amdgcn_global_load_lds(
      (const __attribute__((address_space(1))) unsigned int*)g,
      (__attribute__((address_space(3))) unsigned int*)l, 16, 0, 0);
}

// ---------------- fp32 -> bf16 cast ----------------
__global__ void cast_bf16_k(const float* __restrict__ in, ushort* __restrict__ out, int n) {
  int i = (blockIdx.x * blockDim.x + threadIdx.x) * 4;
  if (i >= n) return;
  const float4 v = *(const float4*)(in + i);
  ushort4 o;
  o.x = f2bf(v.x); o.y = f2bf(v.y); o.z = f2bf(v.z); o.w = f2bf(v.w);
  *(ushort4*)(out + i) = o;
}

// ---------------- T5 relative-position bias table ----------------
__global__ void build_bias_k(const float* __restrict__ rel_emb, float* __restrict__ biasTab) {
  int d = blockIdx.x * blockDim.x + threadIdx.x;
  if (d >= NBIAS_) return;
  int rp = d - (S_ - 1);
  int ret = (rp > 0) ? 16 : 0;
  int arp = rp < 0 ? -rp : rp;
  int bucket;
  if (arp < 8) {
    bucket = ret + arp;
  } else {
    float t = logf((float)arp * 0.125f);
    t = t / 2.772588722239781f;
    t = t * 8.0f;
    int large = 8 + (int)t;
    if (large > 15) large = 15;
    bucket = ret + large;
  }
  for (int h = 0; h < H_; ++h)
    biasTab[h * NBIAS_ + d] = rel_emb[bucket * H_ + h];
}

// ---------------- shared BK=64 GEMM core: C(128x128) = A @ B^T ----------------
// XOR-swizzled LDS (16B slot ^= row&7): frag ds_read_b128 lands ~2-way (free).
__device__ __forceinline__ void gemm_core(
    const ushort* __restrict__ gA, const ushort* __restrict__ gB,
    ushort* As, ushort* Bs, f32x4 (&acc)[4][4],
    int m0, int n0, int wave, int lane)
{
  const int l15 = lane & 15, quad = lane >> 4;
  const int wm = wave >> 1, wn = wave & 1;
  const int srow = lane >> 3;
  const int sw = ((lane & 7) ^ (lane >> 3)) * 8;   // swizzled source col
  const int px = l15 & 7;

  for (int k0 = 0; k0 < DM_; k0 += 64) {
    __syncthreads();
#pragma unroll
    for (int i = 0; i < 8; ++i) {
      int c = wave * 8 + i;                         // 0..31: 16 A-chunks, 16 B-chunks
      if (c < 16)
        ldg16_lds(gA + (size_t)(m0 + c * 8 + srow) * DM_ + k0 + sw, As + c * 512);
      else
        ldg16_lds(gB + (size_t)(n0 + (c - 16) * 8 + srow) * DM_ + k0 + sw, Bs + (c - 16) * 512);
    }
    __syncthreads();
#pragma unroll
    for (int kk = 0; kk < 2; ++kk) {
      short8 af[4], bfr[4];
#pragma unroll
      for (int mi = 0; mi < 4; ++mi)
        af[mi] = *(const short8*)&As[(wm * 64 + mi * 16 + l15) * 64 + (((kk * 4 + quad) ^ px)) * 8];
#pragma unroll
      for (int ni = 0; ni < 4; ++ni)
        bfr[ni] = *(const short8*)&Bs[(wn * 64 + ni * 16 + l15) * 64 + (((kk * 4 + quad) ^ px)) * 8];
#pragma unroll
      for (int mi = 0; mi < 4; ++mi)
#pragma unroll
        for (int ni = 0; ni < 4; ++ni)
          acc[mi][ni] = MFMA16(af[mi], bfr[ni], acc[mi][ni]);
    }
  }
}

// ---------------- QKV projection ----------------
// z: 0->Q [b,h,s,dh], 1->K [b,h,s,dh], 2->V^T [b,h,dh,s] (via LDS transpose, coalesced)
__global__ __launch_bounds__(256) void gemm_qkv_k(
    const ushort* __restrict__ X,
    const ushort* __restrict__ Wq, const ushort* __restrict__ Wk, const ushort* __restrict__ Wv,
    ushort* __restrict__ Q, ushort* __restrict__ K, ushort* __restrict__ Vt)
{
  __shared__ __align__(16) ushort sh[17408];      // 34 KB: As|Bs (8K+8K), or 128x136 transpose
  ushort* As = sh;
  ushort* Bs = sh + 8192;
  const int z = blockIdx.z;
  const ushort* __restrict__ W = (z == 0) ? Wq : (z == 1) ? Wk : Wv;
  const int tid = threadIdx.x;
  const int wave = tid >> 6, lane = tid & 63;
  const int l15 = lane & 15, quad = lane >> 4;
  const int wm = wave >> 1, wn = wave & 1;
  const int m0 = blockIdx.y * 128;
  const int n0 = blockIdx.x * 128;

  f32x4 acc[4][4];
#pragma unroll
  for (int mi = 0; mi < 4; ++mi)
#pragma unroll
    for (int ni = 0; ni < 4; ++ni) acc[mi][ni] = (f32x4){0.f, 0.f, 0.f, 0.f};

  gemm_core(X, W, As, Bs, acc, m0, n0, wave, lane);

  if (z < 2) {
    ushort* dst = (z == 0) ? Q : K;
#pragma unroll
    for (int mi = 0; mi < 4; ++mi)
#pragma unroll
      for (int ni = 0; ni < 4; ++ni)
#pragma unroll
        for (int r = 0; r < 4; ++r) {
          int m = m0 + wm * 64 + mi * 16 + quad * 4 + r;   // token
          int n = n0 + wn * 64 + ni * 16 + l15;            // d_model col
          int b = m >> 11, s = m & (S_ - 1);
          int hh = n >> 6, dd = n & 63;
          dst[((size_t)(b * H_ + hh) * S_ + s) * DH_ + dd] = f2bf(acc[mi][ni][r]);
        }
  } else {
    // transpose through LDS -> coalesced b128 stores of V^T
    __syncthreads();
#pragma unroll
    for (int mi = 0; mi < 4; ++mi)
#pragma unroll
      for (int ni = 0; ni < 4; ++ni) {
        int n = wn * 64 + ni * 16 + l15;
        int m = wm * 64 + mi * 16 + quad * 4;
        ushort4 w4;
        w4.x = f2bf(acc[mi][ni][0]); w4.y = f2bf(acc[mi][ni][1]);
        w4.z = f2bf(acc[mi][ni][2]); w4.w = f2bf(acc[mi][ni][3]);
        *(ushort4*)&sh[n * 136 + m] = w4;                  // stride 136 -> conflict-light
      }
    __syncthreads();
    const int b = m0 >> 11, s0 = m0 & (S_ - 1);
#pragma unroll
    for (int p = 0; p < 8; ++p) {
      int task = p * 256 + tid;              // 128 n x 16 m-chunks
      int n = task >> 4, mc = (task & 15) * 8;
      int col = n0 + n, hh = col >> 6, dd = col & 63;
      *(short8*)(Vt + ((size_t)(b * H_ + hh) * DH_ + dd) * S_ + s0 + mc) =
          *(const short8*)&sh[n * 136 + mc];
    }
  }
}

// ---------------- Output projection: out = Ctx @ Wo^T (fp32) ----------------
__global__ __launch_bounds__(256) void gemm_out_k(
    const ushort* __restrict__ A, const ushort* __restrict__ W, float* __restrict__ out)
{
  __shared__ __align__(16) ushort sh[16384];
  ushort* As = sh;
  ushort* Bs = sh + 8192;
  const int tid = threadIdx.x;
  const int wave = tid >> 6, lane = tid & 63;
  const int l15 = lane & 15, quad = lane >> 4;
  const int wm = wave >> 1, wn = wave & 1;
  const int m0 = blockIdx.y * 128;
  const int n0 = blockIdx.x * 128;

  f32x4 acc[4][4];
#pragma unroll
  for (int mi = 0; mi < 4; ++mi)
#pragma unroll
    for (int ni = 0; ni < 4; ++ni) acc[mi][ni] = (f32x4){0.f, 0.f, 0.f, 0.f};

  gemm_core(A, W, As, Bs, acc, m0, n0, wave, lane);

#pragma unroll
  for (int mi = 0; mi < 4; ++mi)
#pragma unroll
    for (int ni = 0; ni < 4; ++ni)
#pragma unroll
      for (int r = 0; r < 4; ++r) {
        int m = m0 + wm * 64 + mi * 16 + quad * 4 + r;
        int n = n0 + wn * 64 + ni * 16 + l15;
        out[(size_t)m * DM_ + n] = acc[mi][ni][r];
      }
}

// ---------------- Flash attention: key-sliced waves, transposed QK, P in registers ----------------
// Block: 4 waves, 64 q-rows, full 2048 keys in 64-key tiles. Wave w owns key slice
// [w*16, w*16+16) of every tile. S^T = K·Q^T (A=K, B=Q) puts P directly in the
// A-operand layout of a half-zeroed 16x16x32 PV mfma -> no P LDS round-trip.
// No online max (scores bounded; softmax shift-invariant); partial O/l are additive
// across waves -> one LDS reduce at the end. K/V staged via XOR-swizzled ldg16.
// NOTE: epilogue reduce loop MUST be fully unrolled — a runtime index into of[][]
// forces the accumulators to scratch for the whole kernel (r5: 2.1 GB HBM writes).
__global__ __launch_bounds__(256, 2) void attn_k(
    const ushort* __restrict__ Q, const ushort* __restrict__ K, const ushort* __restrict__ Vt,
    const float* __restrict__ biasTab, ushort* __restrict__ Ctx)
{
  __shared__ __align__(16) ushort KV[8192];   // Ks[64key][64dh] | Vs[64dh][64key], swizzled
  __shared__ float bias_s[2111];              // this block's bias window
  ushort* Ks = KV;
  ushort* Vs = KV + 4096;

  const int tid = threadIdx.x;
  const int wave = tid >> 6, lane = tid & 63;  // wave = key-slice id
  const int l15 = lane & 15, quad = lane >> 4;
  const int bh = blockIdx.y;
  const int h = bh & (H_ - 1);
  const int b = bh >> 4;
  const int qb = blockIdx.x * 64;
  const int srow = lane >> 3;
  const int sw = ((lane & 7) ^ (lane >> 3)) * 8;  // swizzled source col (elements)

  const f32x4 zero4 = {0.f, 0.f, 0.f, 0.f};

  // bias_s[i] = bias[delta + 2047] with i = delta + qb + 63
  for (int i = tid; i < 2111; i += 256)
    bias_s[i] = biasTab[h * NBIAS_ + 1984 - qb + i];

  const ushort* Qh = Q  + (size_t)bh * S_ * DH_;
  const ushort* Kh = K  + (size_t)bh * S_ * DH_;
  const ushort* Vh = Vt + (size_t)bh * DH_ * S_;

  // Q B-frags: B[n=qrow=l15][k=dh], 64 rows x 64 dh -> 8 frags, kept in registers
  short8 qf[4][2];
#pragma unroll
  for (int nf = 0; nf < 4; ++nf)
#pragma unroll
    for (int kk = 0; kk < 2; ++kk)
      qf[nf][kk] = *(const short8*)(Qh + (size_t)(qb + nf * 16 + l15) * DH_ + kk * 32 + quad * 8);

  short8 oneh;                                 // {1,1,1,1,0,0,0,0} bf16
#pragma unroll
  for (int i = 0; i < 8; ++i) oneh[i] = (i < 4) ? (short)0x3F80 : (short)0;

  f32x4 of[4][4];                              // O[qrow nf][dh nt] partial
#pragma unroll
  for (int nf = 0; nf < 4; ++nf)
#pragma unroll
    for (int nt = 0; nt < 4; ++nt) of[nf][nt] = zero4;
  f32x4 ls[4];
#pragma unroll
  for (int nf = 0; nf < 4; ++nf) ls[nf] = zero4;

  const int kidx = (wave * 16 + l15) * 64;     // K row base (elements)
  const int vslot = wave * 2 + (quad >> 1);    // V logical 16B slot for this wave/quad

  for (int kt = 0; kt < S_; kt += 64) {
    __syncthreads();                           // prior tile's LDS reads done
#pragma unroll
    for (int i = 0; i < 2; ++i) {              // 16 chunks / 4 waves: K chunks 0..7, V 8..15
      int c = wave * 2 + i;
      ldg16_lds(Kh + (size_t)(kt + c * 8 + srow) * DH_ + sw, Ks + c * 512);
      ldg16_lds(Vh + (size_t)(c * 8 + srow) * S_ + kt + sw, Vs + c * 512);
    }
    __syncthreads();                           // drains vmcnt

    // ---- S^T = K·Q^T for this wave's 16 keys x 64 q-rows ----
    short8 kf0 = *(const short8*)&Ks[kidx + ((quad ^ (l15 & 7))) * 8];
    short8 kf1 = *(const short8*)&Ks[kidx + (((4 + quad) ^ (l15 & 7))) * 8];
    f32x4 sc[4];
#pragma unroll
    for (int nf = 0; nf < 4; ++nf) {
      sc[nf] = MFMA16(kf0, qf[nf][0], zero4);
      sc[nf] = MFMA16(kf1, qf[nf][1], sc[nf]);
    }

    // ---- bias + exp (no max); result packed straight into PV A-frags ----
    short8 pf[4];
    const int ib = kt + wave * 16 + quad * 4 + 63 - l15;
#pragma unroll
    for (int nf = 0; nf < 4; ++nf) {
      const int i0 = ib - nf * 16;
      pf[nf][0] = (short)f2bf_fast(__expf(sc[nf][0] * 0.125f + bias_s[i0]));
      pf[nf][1] = (short)f2bf_fast(__expf(sc[nf][1] * 0.125f + bias_s[i0 + 1]));
      pf[nf][2] = (short)f2bf_fast(__expf(sc[nf][2] * 0.125f + bias_s[i0 + 2]));
      pf[nf][3] = (short)f2bf_fast(__expf(sc[nf][3] * 0.125f + bias_s[i0 + 3]));
      pf[nf][4] = 0; pf[nf][5] = 0; pf[nf][6] = 0; pf[nf][7] = 0;
    }

    // ---- row-sum + PV (half-zero k=16 mfma) ----
#pragma unroll
    for (int nf = 0; nf < 4; ++nf) ls[nf] = MFMA16(pf[nf], oneh, ls[nf]);
#pragma unroll
    for (int nt = 0; nt < 4; ++nt) {
      ushort4 v4 = *(const ushort4*)&Vs[(nt * 16 + l15) * 64 +
                                        ((vslot ^ (l15 & 7))) * 8 + (quad & 1) * 4];
      short8 vf;
      vf[0] = (short)v4.x; vf[1] = (short)v4.y; vf[2] = (short)v4.z; vf[3] = (short)v4.w;
      vf[4] = 0; vf[5] = 0; vf[6] = 0; vf[7] = 0;
#pragma unroll
      for (int nf = 0; nf < 4; ++nf)
        of[nf][nt] = MFMA16(pf[nf], vf, of[nf][nt]);
    }
  }

  // ---- cross-wave reduce (partials additive) + store. FULLY UNROLLED (see note) ----
  __syncthreads();
  float* red = (float*)KV;                     // 16 KB scratch
#pragma unroll
  for (int mi = 0; mi < 4; ++mi) {
    if (wave) {
      int base = ((wave - 1) * 64 + lane) * 21;
#pragma unroll
      for (int nt = 0; nt < 4; ++nt)
#pragma unroll
        for (int r = 0; r < 4; ++r) red[base + nt * 4 + r] = of[mi][nt][r];
#pragma unroll
      for (int r = 0; r < 4; ++r) red[base + 16 + r] = ls[mi][r];
    }
    __syncthreads();
    if (wave == 0) {
#pragma unroll
      for (int w = 1; w < 4; ++w) {
        int base = ((w - 1) * 64 + lane) * 21;
#pragma unroll
        for (int nt = 0; nt < 4; ++nt)
#pragma unroll
          for (int r = 0; r < 4; ++r) of[mi][nt][r] += red[base + nt * 4 + r];
#pragma unroll
        for (int r = 0; r < 4; ++r) ls[mi][r] += red[base + 16 + r];
      }
#pragma unroll
      for (int nt = 0; nt < 4; ++nt)
#pragma unroll
        for (int r = 0; r < 4; ++r) {
          int t = b * S_ + qb + mi * 16 + quad * 4 + r;
          Ctx[(size_t)t * DM_ + h * 64 + nt * 16 + l15] = f2bf(of[mi][nt][r] / ls[mi][r]);
        }
    }
    __syncthreads();
  }
}

// ---------------- launch ----------------
extern "C" void kernel_launch(void* const* d_in, const int* in_sizes, int n_in,
                              void* d_out, int out_size, void* d_ws, size_t ws_size,
                              hipStream_t stream) {
  const float* hs  = (const float*)d_in[0];
  const float* Wq  = (const float*)d_in[1];
  const float* Wk  = (const float*)d_in[2];
  const float* Wv  = (const float*)d_in[3];
  const float* Wo  = (const float*)d_in[4];
  const float* rel = (const float*)d_in[5];
  float* out = (float*)d_out;

  ushort* Xb  = (ushort*)d_ws;                          // 4096x1024
  ushort* Wqb = Xb  + (size_t)NTOK_ * DM_;              // 1024x1024 each
  ushort* Wkb = Wqb + (size_t)DM_ * DM_;
  ushort* Wvb = Wkb + (size_t)DM_ * DM_;
  ushort* Wob = Wvb + (size_t)DM_ * DM_;
  ushort* Qd  = Wob + (size_t)DM_ * DM_;                // [b][h][s][dh]
  ushort* Kd  = Qd  + (size_t)NTOK_ * DM_;
  ushort* Vtd = Kd  + (size_t)NTOK_ * DM_;              // [b][h][dh][s]
  float* biasTab = (float*)(Vtd + (size_t)NTOK_ * DM_); // [H][4095]
  ushort* Ctx = Xb;                                     // alias: X dead after QKV GEMM

  cast_bf16_k<<<4096, 256, 0, stream>>>(hs, Xb, NTOK_ * DM_);
  cast_bf16_k<<<1024, 256, 0, stream>>>(Wq, Wqb, DM_ * DM_);
  cast_bf16_k<<<1024, 256, 0, stream>>>(Wk, Wkb, DM_ * DM_);
  cast_bf16_k<<<1024, 256, 0, stream>>>(Wv, Wvb, DM_ * DM_);
  cast_bf16_k<<<1024, 256, 0, stream>>>(Wo, Wob, DM_ * DM_);
  build_bias_k<<<16, 256, 0, stream>>>(rel, biasTab);

  gemm_qkv_k<<<dim3(8, 32, 3), 256, 0, stream>>>(Xb, Wqb, Wkb, Wvb, Qd, Kd, Vtd);
  attn_k<<<dim3(S_ / 64, 2 * H_), 256, 0, stream>>>(Qd, Kd, Vtd, biasTab, Ctx);
  gemm_out_k<<<dim3(8, 32), 256, 0, stream>>>(Ctx, Wob, out);
}